// Round 11
// baseline (3736.139 us; speedup 1.0000x reference)
//
#include <hip/hip_runtime.h>

typedef unsigned short u16;

constexpr int MQ   = 131072;
constexpr int NPTS = 1024;

// ---- np-exact f32 arithmetic: no FMA contraction, np's association order ----
__device__ __forceinline__ float np_sq3(float x, float y, float z){
  #pragma clang fp contract(off)
  float s = (x*x + y*y) + z*z;
  return s;
}
__device__ __forceinline__ float np_d2(float a2, float b2,
                                       float c0, float c1, float c2,
                                       float p0, float p1, float p2){
  #pragma clang fp contract(off)
  float dot = (c0*p0 + c1*p1) + c2*p2;
  float d   = (a2 + b2) - 2.0f*dot;
  return d;
}

// ---------- host-sanity failure marker (f32 output!) ----------
__global__ void k_err_r11(float code, float* __restrict__ out){
  out[0] = code;
}

// ---------- prep: zero denom, pack points {x,y,z,|p|^2 np-exact} ----------
__global__ __launch_bounds__(256) void k_prep_r11(const float* __restrict__ pts,
                                                  float4* __restrict__ pts4,
                                                  float* __restrict__ denom){
  int i = blockIdx.x*256 + threadIdx.x;          // 2048 threads
  if (i < 8) denom[i] = 0.f;
  if (i < 2*NPTS){
    float x = pts[i*3+0], y = pts[i*3+1], z = pts[i*3+2];
    pts4[i] = make_float4(x, y, z, np_sq3(x,y,z));
  }
}

// ---------- pass 1: denom[n][k] = sum_m 1/dist ----------
__global__ __launch_bounds__(256) void k_denom_r11(const float* __restrict__ coords,
                                                   const float4* __restrict__ pts4,
                                                   float* __restrict__ denom){
  __shared__ float red[4][4];
  int n = blockIdx.y;
  int m = blockIdx.x*256 + threadIdx.x;
  size_t g = (size_t)n*MQ + m;
  float c0 = coords[g*3+0], c1 = coords[g*3+1], c2 = coords[g*3+2];
  float a2 = np_sq3(c0,c1,c2);
  const float4* pp = pts4 + n*NPTS;
  float bd0=1e30f,bd1=1e30f,bd2=1e30f,bd3=1e30f;
  for (int p = 0; p < NPTS; ++p){
    float4 q = pp[p];
    float d = np_d2(a2, q.w, c0,c1,c2, q.x,q.y,q.z);
    if (d < bd3){
      if (d < bd2){
        bd3=bd2;
        if (d < bd1){ bd2=bd1; if (d < bd0){ bd1=bd0; bd0=d; } else bd1=d; }
        else bd2=d;
      } else bd3=d;
    }
  }
  float w0 = 1.f/bd0, w1 = 1.f/bd1, w2 = 1.f/bd2, w3 = 1.f/bd3;
  #pragma unroll
  for (int off=32; off>0; off>>=1){
    w0 += __shfl_down(w0, off); w1 += __shfl_down(w1, off);
    w2 += __shfl_down(w2, off); w3 += __shfl_down(w3, off);
  }
  int lane = threadIdx.x & 63, wv = threadIdx.x >> 6;
  if (lane == 0){ red[wv][0]=w0; red[wv][1]=w1; red[wv][2]=w2; red[wv][3]=w3; }
  __syncthreads();
  if (threadIdx.x < 4){
    int k = threadIdx.x;
    atomicAdd(&denom[n*4+k], red[0][k]+red[1][k]+red[2][k]+red[3][k]);
  }
}

// ------- per-thread layer, f32 weights in LDS [IN][OUT], broadcast reads -------
template<int IN, int OUT, bool RELU>
__device__ __forceinline__ void layer_lds(const float* in, float* out,
                                          const float* __restrict__ w, const float* __restrict__ b){
  #pragma unroll 1
  for (int jb = 0; jb < OUT/8; ++jb){
    float a[8];
    #pragma unroll
    for (int j=0;j<8;++j) a[j] = b[jb*8+j];
    #pragma unroll
    for (int i = 0; i < IN; ++i){
      float4 wA = *(const float4*)(w + i*OUT + jb*8);
      float4 wB = *(const float4*)(w + i*OUT + jb*8 + 4);
      float x = in[i];
      a[0]=fmaf(x,wA.x,a[0]); a[1]=fmaf(x,wA.y,a[1]); a[2]=fmaf(x,wA.z,a[2]); a[3]=fmaf(x,wA.w,a[3]);
      a[4]=fmaf(x,wB.x,a[4]); a[5]=fmaf(x,wB.y,a[5]); a[6]=fmaf(x,wB.z,a[6]); a[7]=fmaf(x,wB.w,a[7]);
    }
    #pragma unroll
    for (int j=0;j<8;++j) out[jb*8+j] = RELU ? fmaxf(a[j], 0.f) : a[j];
  }
}

// ------- staged layer: GLOBAL f32 weights sliced through LDS; uniform control flow -------
template<int IN, int OUT, bool RELU, bool INIT>
__device__ __forceinline__ void layer_staged(const float* in, float* out,
                                             const float* __restrict__ gw, const float* b,
                                             float* sbuf, int tid){
  #pragma unroll 1
  for (int jb = 0; jb < OUT/8; ++jb){
    __syncthreads();
    for (int idx = tid; idx < IN*8; idx += 256){
      int i = idx >> 3, j = idx & 7;
      sbuf[idx] = gw[i*OUT + jb*8 + j];
    }
    __syncthreads();
    float a[8];
    #pragma unroll
    for (int j=0;j<8;++j) a[j] = INIT ? b[jb*8+j] : out[jb*8+j];
    #pragma unroll 2
    for (int i = 0; i < IN; ++i){
      float4 wA = *(const float4*)(sbuf + i*8);
      float4 wB = *(const float4*)(sbuf + i*8 + 4);
      float x = in[i];
      a[0]=fmaf(x,wA.x,a[0]); a[1]=fmaf(x,wA.y,a[1]); a[2]=fmaf(x,wA.z,a[2]); a[3]=fmaf(x,wA.w,a[3]);
      a[4]=fmaf(x,wB.x,a[4]); a[5]=fmaf(x,wB.y,a[5]); a[6]=fmaf(x,wB.z,a[6]); a[7]=fmaf(x,wB.w,a[7]);
    }
    #pragma unroll
    for (int j=0;j<8;++j) out[jb*8+j] = RELU ? fmaxf(a[j], 0.f) : a[j];
  }
}

__global__ __launch_bounds__(256) void k_main_r11(
    const float* __restrict__ coords, const float* __restrict__ dirs,
    const float* __restrict__ planes, const float* __restrict__ pemb,
    const float* __restrict__ qw1, const float* __restrict__ qb1,
    const float* __restrict__ qw2, const float* __restrict__ qb2,
    const float* __restrict__ fw1, const float* __restrict__ fb1,
    const float* __restrict__ fw2, const float* __restrict__ fb2,
    const float* __restrict__ fw3, const float* __restrict__ fb3,
    const float* __restrict__ dw,  const float* __restrict__ db,
    const float* __restrict__ rw1, const float* __restrict__ rb1,
    const float* __restrict__ rw2, const float* __restrict__ rb2,
    const float4* __restrict__ pts4, const float* __restrict__ denom,
    float* __restrict__ out)
{
  __shared__ __align__(16) float s_qw1[59*64];
  __shared__ __align__(16) float s_qw2[64*32];
  __shared__ __align__(16) float sbuf[155*8];
  __shared__ float s_dw[128], s_rw2[192];
  __shared__ float s_qb1[64], s_qb2[32], s_fb1[128], s_fb2[128], s_fb3[128], s_rb1[64], s_rb2[4], s_db[1];

  int tid = threadIdx.x;
  for (int i = tid; i < 59*64; i += 256) s_qw1[i] = qw1[i];
  for (int i = tid; i < 64*32; i += 256) s_qw2[i] = qw2[i];
  if (tid < 192) s_rw2[tid] = rw2[tid];
  if (tid < 128){ s_dw[tid]=dw[tid]; s_fb1[tid]=fb1[tid]; s_fb2[tid]=fb2[tid]; s_fb3[tid]=fb3[tid]; }
  if (tid < 64){ s_qb1[tid]=qb1[tid]; s_rb1[tid]=rb1[tid]; }
  if (tid < 32) s_qb2[tid]=qb2[tid];
  if (tid < 3)  s_rb2[tid]=rb2[tid];
  if (tid == 0) s_db[0] = db[0];
  __syncthreads();

  int n = blockIdx.x >> 9;
  int m = ((blockIdx.x & 511) << 8) + tid;
  size_t g = (size_t)n*MQ + m;

  float c0 = coords[g*3+0], c1 = coords[g*3+1], c2 = coords[g*3+2];
  bool sel = (c0 > -1.f) && (c0 < 1.f) && (c1 > -1.f) && (c1 < 1.f) && (c2 > -1.f) && (c2 < 1.f);

  // ---- triplane bilinear sample from (N,3,C,H,W) f32, mean over planes ----
  float feat0[64];
  #pragma unroll
  for (int c=0;c<64;++c) feat0[c]=0.f;
  float gxs[3] = {c0, c0, c2};
  float gys[3] = {c1, c2, c1};
  #pragma unroll 1
  for (int pl=0; pl<3; ++pl){
    float ix = ((gxs[pl] + 1.f)*256.f - 1.f)*0.5f;
    float iy = ((gys[pl] + 1.f)*256.f - 1.f)*0.5f;
    float x0f = floorf(ix), y0f = floorf(iy);
    int x0 = (int)x0f, y0 = (int)y0f;
    float wxb = ix - x0f, wxa = (x0f + 1.f) - ix;
    float wyb = iy - y0f, wya = (y0f + 1.f) - iy;
    const float* pb = planes + ((size_t)(n*3+pl) << 21);
    int   xs[4] = {x0, x0+1, x0,   x0+1};
    int   ys[4] = {y0, y0,   y0+1, y0+1};
    float wt[4] = {wxa*wya, wxb*wya, wxa*wyb, wxb*wyb};
    #pragma unroll
    for (int t=0;t<4;++t){
      int xi = xs[t], yi = ys[t];
      if (xi>=0 && xi<256 && yi>=0 && yi<256){
        const float* tp = pb + ((yi<<8)+xi);
        float wv = wt[t];
        #pragma unroll
        for (int c=0;c<32;++c) feat0[c] = fmaf(wv, tp[(size_t)c<<16], feat0[c]);
      }
    }
  }
  #pragma unroll
  for (int c=0;c<32;++c) feat0[c] *= (1.f/3.f);

  // ---- kNN: np-exact d2 (bit-identical to k_denom_r11) ----
  float a2 = np_sq3(c0,c1,c2);
  const float4* ppts = pts4 + n*NPTS;
  float bd0=1e30f,bd1=1e30f,bd2=1e30f,bd3=1e30f;
  int   bi0=0,bi1=0,bi2=0,bi3=0;
  for (int p = 0; p < NPTS; ++p){
    float4 q = ppts[p];
    float d = np_d2(a2, q.w, c0,c1,c2, q.x,q.y,q.z);
    if (d < bd3){
      if (d < bd2){
        bd3=bd2; bi3=bi2;
        if (d < bd1){
          bd2=bd1; bi2=bi1;
          if (d < bd0){ bd1=bd0; bi1=bi0; bd0=d; bi0=p; }
          else        { bd1=d;   bi1=p; }
        } else        { bd2=d;   bi2=p; }
      } else          { bd3=d;   bi3=p; }
    }
  }
  float ddv[4] = {bd0,bd1,bd2,bd3};
  int   iiv[4] = {bi0,bi1,bi2,bi3};
  float wkv[4];
  #pragma unroll
  for (int k=0;k<4;++k) wkv[k] = (1.f/ddv[k]) / denom[n*4+k];

  #pragma unroll 1
  for (int k=0;k<4;++k){
    int j = iiv[k];
    float hin[59];
    #pragma unroll
    for (int q=0;q<32;++q) hin[q] = pemb[j*32+q];
    float4 pq = ppts[j];
    float vx = c0 - pq.x, vy = c1 - pq.y, vz = c2 - pq.z;
    float nr = fmaxf(sqrtf(vx*vx + vy*vy + vz*vz), 1e-12f);
    float r0 = vx/nr, r1 = vy/nr, r2 = vz/nr;
    float rr[3] = {r0, r1, r2};
    #pragma unroll
    for (int d3=0; d3<3; ++d3){
      #pragma unroll
      for (int f=0; f<4; ++f){
        float e = rr[d3]*(float)(1<<f);
        hin[32 + d3*4 + f] = __sinf(e);
        hin[44 + d3*4 + f] = __cosf(e);
      }
    }
    hin[56]=r0; hin[57]=r1; hin[58]=r2;
    float h1[64]; layer_lds<59,64,true >(hin, h1, s_qw1, s_qb1);
    float h2[32]; layer_lds<64,32,false>(h1, h2, s_qw2, s_qb2);
    float wk = wkv[k];
    #pragma unroll
    for (int c=0;c<32;++c) feat0[32+c] = fmaf(wk, h2[c], feat0[32+c]);
  }

  // ---- feature MLP ----
  float f1[128];   layer_staged<64,128,true,true >(feat0, f1,  fw1, s_fb1, sbuf, tid);
  float f2[128];   layer_staged<128,128,true,true>(f1,   f2,  fw2, s_fb2, sbuf, tid);
  float feat[128]; layer_staged<128,128,false,true>(f2, feat, fw3, s_fb3, sbuf, tid);

  // ---- density head ----
  float dacc = s_db[0];
  #pragma unroll
  for (int i=0;i<128;++i) dacc = fmaf(feat[i], s_dw[i], dacc);
  float z  = 10.f*dacc;
  float sp = (z > 0.f) ? (z + log1pf(__expf(-z))) : log1pf(__expf(z));
  float raw = sp*0.1f*(sel ? 1.f : 0.f);
  float dens = 1.f - __expf(-raw);

  // ---- rgb head ----
  float dx = dirs[g*3+0], dy = dirs[g*3+1], dz = dirs[g*3+2];
  float dn = fmaxf(sqrtf(dx*dx+dy*dy+dz*dz), 1e-12f);
  float n0 = dx/dn, n1 = dy/dn, n2 = dz/dn;
  float ext[27];
  float nn3[3] = {n0,n1,n2};
  #pragma unroll
  for (int d3=0; d3<3; ++d3){
    #pragma unroll
    for (int f=0; f<4; ++f){
      float e = nn3[d3]*(float)(1<<f);
      ext[d3*4 + f]      = __sinf(e);
      ext[12 + d3*4 + f] = __cosf(e);
    }
  }
  ext[24]=n0; ext[25]=n1; ext[26]=n2;
  float r1v[64];
  layer_staged<128,64,false,true>(feat, r1v, rw1,          s_rb1,   sbuf, tid);
  layer_staged<27, 64,true,false>(ext,  r1v, rw1 + 128*64, nullptr, sbuf, tid);
  float o0 = s_rb2[0], o1 = s_rb2[1], o2 = s_rb2[2];
  #pragma unroll
  for (int i=0;i<64;++i){
    float a = r1v[i];
    o0 = fmaf(a, s_rw2[i*3+0], o0);
    o1 = fmaf(a, s_rw2[i*3+1], o1);
    o2 = fmaf(a, s_rw2[i*3+2], o2);
  }
  o0 = 1.f/(1.f+__expf(-o0))*1.002f - 0.001f;
  o1 = 1.f/(1.f+__expf(-o1))*1.002f - 0.001f;
  o2 = 1.f/(1.f+__expf(-o2))*1.002f - 0.001f;

  // ---- outputs (FLOAT32): [densities NM][rgb 3NM][dist 4NM] ----
  out[g] = dens;
  float* orgb = out + 262144;
  orgb[g*3+0]=o0; orgb[g*3+1]=o1; orgb[g*3+2]=o2;
  float4* odist = (float4*)(out + 262144 + 786432);
  odist[g] = make_float4(ddv[0], ddv[1], ddv[2], ddv[3]);
}

extern "C" void kernel_launch(void* const* d_in, const int* in_sizes, int n_in,
                              void* d_out, int out_size, void* d_ws, size_t ws_size,
                              hipStream_t stream){
  static const int expect[21] = {786432, 786432, 6144, 12582912, 32768,
                                 3776, 64, 2048, 32, 8192, 128, 16384, 128, 16384, 128,
                                 128, 1, 9920, 64, 192, 3};
  if (n_in != 21){ k_err_r11<<<1,1,0,stream>>>(128.f, (float*)d_out); return; }
  if (out_size != 2097152){ k_err_r11<<<1,1,0,stream>>>(129.f, (float*)d_out); return; }
  for (int i = 0; i < 21; ++i){
    if (in_sizes[i] != expect[i]){
      k_err_r11<<<1,1,0,stream>>>(130.f + (float)i, (float*)d_out);
      return;
    }
  }

  const float* coords = (const float*)d_in[0];
  const float* dirs   = (const float*)d_in[1];
  const float* pts    = (const float*)d_in[2];
  const float* planes = (const float*)d_in[3];
  const float* pemb   = (const float*)d_in[4];
  const float* qw1 = (const float*)d_in[5];  const float* qb1 = (const float*)d_in[6];
  const float* qw2 = (const float*)d_in[7];  const float* qb2 = (const float*)d_in[8];
  const float* fw1 = (const float*)d_in[9];  const float* fb1 = (const float*)d_in[10];
  const float* fw2 = (const float*)d_in[11]; const float* fb2 = (const float*)d_in[12];
  const float* fw3 = (const float*)d_in[13]; const float* fb3 = (const float*)d_in[14];
  const float* dw  = (const float*)d_in[15]; const float* db  = (const float*)d_in[16];
  const float* rw1 = (const float*)d_in[17]; const float* rb1 = (const float*)d_in[18];
  const float* rw2 = (const float*)d_in[19]; const float* rb2 = (const float*)d_in[20];

  char* ws = (char*)d_ws;
  float*  denom = (float*)ws;              // 8 floats @ 0
  float4* pts4  = (float4*)(ws + 256);     // 2*1024*16 B

  k_prep_r11 <<<8, 256, 0, stream>>>(pts, pts4, denom);
  k_denom_r11<<<dim3(512,2), 256, 0, stream>>>(coords, pts4, denom);
  k_main_r11 <<<1024, 256, 0, stream>>>(coords, dirs, planes, pemb,
      qw1, qb1, qw2, qb2, fw1, fb1, fw2, fb2, fw3, fb3, dw, db, rw1, rb1, rw2, rb2,
      pts4, denom, (float*)d_out);
}